// Round 13
// baseline (652.025 us; speedup 1.0000x reference)
//
#include <hip/hip_runtime.h>
#include <hip/hip_bf16.h>

typedef __attribute__((ext_vector_type(4))) float f32x4;
typedef __attribute__((ext_vector_type(2))) unsigned int u32x2;
typedef __attribute__((ext_vector_type(8))) short s16x8;
typedef __attribute__((ext_vector_type(8))) __bf16 bf16v8;
typedef __attribute__((ext_vector_type(8))) _Float16 f16v8;
typedef __attribute__((ext_vector_type(4))) _Float16 f16x4;

// LDS layout (bytes) — 80 KB total => 2 blocks/CU (160 KB LDS per CU)
#define LDS_X  0        // 32768: x window bf16 [64][256] swz512 (persistent both halves)
#define LDS_Q  32768    // 16384: Q-half bf16 [64][128] swz256; attn fp16 after phase2
#define LDS_K  49152    // 16384: K-half bf16 [64][128] swz256
#define LDS_VT 65536    // 16384: V^T-half fp16 [128][64] swz128
#define LDS_TOT 81920

__device__ __forceinline__ f32x4 mfma16(s16x8 a, s16x8 b, f32x4 c) {
  return __builtin_amdgcn_mfma_f32_16x16x32_bf16(
      __builtin_bit_cast(bf16v8, a), __builtin_bit_cast(bf16v8, b), c, 0, 0, 0);
}
__device__ __forceinline__ f32x4 mfma16h(s16x8 a, s16x8 b, f32x4 c) {
  return __builtin_amdgcn_mfma_f32_16x16x32_f16(
      __builtin_bit_cast(f16v8, a), __builtin_bit_cast(f16v8, b), c, 0, 0, 0);
}
__device__ __forceinline__ f32x4 mfmah16(f16x4 a, f16x4 b, f32x4 c) {
  return __builtin_amdgcn_mfma_f32_16x16x16f16(a, b, c, 0, 0, 0);
}

// HW pair converts
__device__ __forceinline__ unsigned int cvt2(float a, float b) {   // 2x bf16, RNE
  __hip_bfloat162 r = __float22bfloat162_rn(make_float2(a, b));
  unsigned int u;
  __builtin_memcpy(&u, &r, 4);
  return u;
}
__device__ __forceinline__ unsigned int cvt2h(float a, float b) {  // 2x fp16, RTZ
  auto r = __builtin_amdgcn_cvt_pkrtz(a, b);
  unsigned int u;
  __builtin_memcpy(&u, &r, 4);
  return u;
}
__device__ __forceinline__ f16x4 pack4h(float a, float b, float c, float d) {
  u32x2 u;
  u.x = cvt2h(a, b);
  u.y = cvt2h(c, d);
  f16x4 r;
  __builtin_memcpy(&r, &u, 8);
  return r;
}

__device__ __forceinline__ short f2bf(float f) {
  unsigned u = __float_as_uint(f);
  u += 0x7fffu + ((u >> 16) & 1u);
  return (short)(u >> 16);
}

__device__ __forceinline__ int swz512(int row, int colByte) {
  return row * 512 + (colByte ^ ((row & 7) << 4));
}
__device__ __forceinline__ int swz256(int row, int colByte) {
  return row * 256 + (colByte ^ ((row & 7) << 4));
}
__device__ __forceinline__ int swz128(int row, int colByte) {
  return row * 128 + (colByte ^ ((row & 7) << 4));
}

// Prep: WqkvT[n][k] bf16 (768x256); WoutT[n][k] fp16 (256x256);
// RELT[var][h][qt][strip][lane][r] f32 = masked rel_pos in simT C-frag order.
__global__ void prep_w(const float* __restrict__ Wqkv, const float* __restrict__ Wout,
                       const float* __restrict__ relp,
                       short* __restrict__ wqkvT, short* __restrict__ wH,
                       float* __restrict__ relt) {
  int t = blockIdx.x * 256 + threadIdx.x;
  if (t < 768 * 256) {
    int n = t >> 8, k = t & 255;
    wqkvT[t] = f2bf(Wqkv[k * 768 + n]);
  } else if (t < 768 * 256 + 256 * 256) {
    int t2 = t - 768 * 256;
    int n = t2 >> 8, k = t2 & 255;
    _Float16 h = (_Float16)Wout[k * 256 + n];
    unsigned short us;
    __builtin_memcpy(&us, &h, 2);
    wH[t2] = (short)us;
  } else {
    int u = t - 768 * 256 - 256 * 256;   // 0 .. 131071
    int r = u & 3, l = (u >> 2) & 63, strip = (u >> 8) & 3;
    int qt = (u >> 10) & 3, h = (u >> 12) & 7, var = (u >> 15) & 3;
    int p = strip * 16 + (l & 15);
    int q = qt * 16 + ((l >> 4) << 2) + r;
    int pi = p >> 3, pj = p & 7, qi = q >> 3, qj = q & 7;
    bool mrow = (var >> 1) & 1, mcol = var & 1;
    bool mk = (mrow && ((pi < 4) != (qi < 4))) || (mcol && ((pj < 4) != (qj < 4)));
    relt[u] = mk ? -1e30f : relp[h * 225 + (pi - qi + 7) * 15 + (pj - qj + 7)];
  }
}

// One block per (batch, window). 512 threads = 8 waves.
// 80 KB LDS + __launch_bounds__(512,4) -> 2 blocks/CU, 4 waves/SIMD (128-reg cap).
// Channel dim processed in two head-halves; out-proj accumulates across halves in regs.
__global__ __launch_bounds__(512, 4) void swin_mfma(
    const float* __restrict__ x, const float* __restrict__ bqkv,
    const float* __restrict__ bout,
    const short* __restrict__ wqkvT, const short* __restrict__ wH,
    const float* __restrict__ relt, float* __restrict__ out)
{
  __shared__ __align__(16) char lds[LDS_TOT];

  const int tx = threadIdx.x;
  const int w  = tx >> 6;         // wave 0..7
  const int l  = tx & 63;         // lane
  const int g  = l >> 4;          // k-group 0..3
  const int li = l & 15;          // row/col within fragment

  const int b   = blockIdx.x >> 10;
  const int wdw = blockIdx.x & 1023;
  const int wh  = wdw >> 5, wwi = wdw & 31;
  const int rvar = ((wh == 31) ? 2 : 0) | ((wwi == 31) ? 1 : 0);

  // ---- Phase 0: stage x window (rolled -4) as bf16 into LDS ----
  for (int i = 0; i < 8; ++i) {
    int idx = tx + i * 512;       // 0..4095
    int p = idx >> 6, c4 = idx & 63;
    int pi = p >> 3, pj = p & 7;
    int sr = (wh * 8 + pi + 4) & 255;
    int sc = (wwi * 8 + pj + 4) & 255;
    f32x4 v = *(const f32x4*)(x + ((((size_t)b * 256 + sr) * 256 + sc) * 256 + c4 * 4));
    u32x2 uu;
    uu.x = cvt2(v[0], v[1]);
    uu.y = cvt2(v[2], v[3]);
    *(u32x2*)(lds + LDS_X + swz512(p, c4 * 8)) = uu;
  }
  __syncthreads();

  f32x4 acc2[2][4];               // out-proj accumulators, carried across halves
  #pragma unroll
  for (int c = 0; c < 2; ++c)
    #pragma unroll
    for (int rb = 0; rb < 4; ++rb)
      acc2[c][rb] = (f32x4){0.f, 0.f, 0.f, 0.f};

  #pragma unroll 1
  for (int hf = 0; hf < 2; ++hf) {
    // ---- Phase 1 (half hf): QKV GEMM for heads hf*4..hf*4+3.
    //      Wave w: one Q col-block, one K col-block, one V col-block (16 cols each).
    {
      f32x4 accq[4], acck[4], accv[4];
      #pragma unroll
      for (int rb = 0; rb < 4; ++rb) {
        accq[rb] = (f32x4){0.f, 0.f, 0.f, 0.f};
        acck[rb] = (f32x4){0.f, 0.f, 0.f, 0.f};
        accv[rb] = (f32x4){0.f, 0.f, 0.f, 0.f};
      }
      const size_t oq = (size_t)(hf * 128 + w * 16 + li) * 256;
      const size_t ok = (size_t)(256 + hf * 128 + w * 16 + li) * 256;
      const size_t ov = (size_t)(512 + hf * 128 + w * 16 + li) * 256;

      #pragma unroll
      for (int kk = 0; kk < 8; ++kk) {
        s16x8 a[4];
        #pragma unroll
        for (int rb = 0; rb < 4; ++rb)
          a[rb] = *(const s16x8*)(lds + LDS_X + swz512(rb * 16 + li, kk * 64 + g * 16));
        s16x8 bq = *(const s16x8*)(wqkvT + oq + kk * 32 + g * 8);
        s16x8 bk = *(const s16x8*)(wqkvT + ok + kk * 32 + g * 8);
        s16x8 bv = *(const s16x8*)(wqkvT + ov + kk * 32 + g * 8);
        #pragma unroll
        for (int rb = 0; rb < 4; ++rb) {
          accq[rb] = mfma16(bq, a[rb], accq[rb]);    // swapped: C[outcol][token]
          acck[rb] = mfma16(bk, a[rb], acck[rb]);
          accv[rb] = mfma16(a[rb], bv, accv[rb]);    // normal:  C[token][vcol]
        }
      }

      // Q store (pre-scaled): row=token rb*16+li, 4 consecutive cols (w*16+g*4+r)
      {
        f32x4 bq4 = *(const f32x4*)(bqkv + hf * 128 + w * 16 + g * 4);
        const float SC = 0.17677669529663687f;
        #pragma unroll
        for (int rb = 0; rb < 4; ++rb) {
          u32x2 uu;
          uu.x = cvt2((accq[rb][0] + bq4[0]) * SC, (accq[rb][1] + bq4[1]) * SC);
          uu.y = cvt2((accq[rb][2] + bq4[2]) * SC, (accq[rb][3] + bq4[3]) * SC);
          *(u32x2*)(lds + LDS_Q + swz256(rb * 16 + li, w * 32 + g * 8)) = uu;
        }
      }
      // K store
      {
        f32x4 bk4 = *(const f32x4*)(bqkv + 256 + hf * 128 + w * 16 + g * 4);
        #pragma unroll
        for (int rb = 0; rb < 4; ++rb) {
          u32x2 uu;
          uu.x = cvt2(acck[rb][0] + bk4[0], acck[rb][1] + bk4[1]);
          uu.y = cvt2(acck[rb][2] + bk4[2], acck[rb][3] + bk4[3]);
          *(u32x2*)(lds + LDS_K + swz256(rb * 16 + li, w * 32 + g * 8)) = uu;
        }
      }
      // V store -> VT[d][token] fp16: row d = w*16+li, 4 consecutive tokens
      {
        const int d = w * 16 + li;
        const float bv = bqkv[512 + hf * 128 + d];
        #pragma unroll
        for (int rb = 0; rb < 4; ++rb) {
          u32x2 uu;
          uu.x = cvt2h(accv[rb][0] + bv, accv[rb][1] + bv);
          uu.y = cvt2h(accv[rb][2] + bv, accv[rb][3] + bv);
          *(u32x2*)(lds + LDS_VT + swz128(d, rb * 32 + g * 8)) = uu;
        }
      }
    }
    __syncthreads();

    // ---- Phase 2 (half hf): attention, 1 unit per wave.
    //      Unit = (head h = w>>1 within half, p-half = w&1). In-register P'->PV. ----
    {
      const int h = w >> 1;            // head within half
      const int ah = hf * 4 + h;       // actual head
      const int phalf = w & 1, p0 = phalf * 32;

      f32x4 simT[2][4];
      #pragma unroll
      for (int pt = 0; pt < 2; ++pt) {
        s16x8 qf = *(const s16x8*)(lds + LDS_Q + swz256(p0 + pt * 16 + li, h * 64 + g * 16));
        #pragma unroll
        for (int qt = 0; qt < 4; ++qt) {
          f32x4 rc = *(const f32x4*)(relt
              + ((((rvar * 8 + ah) * 4 + qt) * 4 + (phalf * 2 + pt)) * 64 + l) * 4);
          s16x8 kf = *(const s16x8*)(lds + LDS_K + swz256(qt * 16 + li, h * 64 + g * 16));
          simT[pt][qt] = mfma16(kf, qf, rc);
        }
      }

      float rinv[2];
      f16x4 pa[2][4];
      #pragma unroll
      for (int pt = 0; pt < 2; ++pt) {
        float s = 0.f;
        #pragma unroll
        for (int qt = 0; qt < 4; ++qt) {
          float e0 = __expf(simT[pt][qt][0]);
          float e1 = __expf(simT[pt][qt][1]);
          float e2 = __expf(simT[pt][qt][2]);
          float e3 = __expf(simT[pt][qt][3]);
          s += (e0 + e1) + (e2 + e3);
          pa[pt][qt] = pack4h(e0, e1, e2, e3);
        }
        s += __shfl_xor(s, 16);
        s += __shfl_xor(s, 32);
        rinv[pt] = 1.0f / s;
      }

      f32x4 at[2][2];
      #pragma unroll
      for (int pt = 0; pt < 2; ++pt)
        #pragma unroll
        for (int dt = 0; dt < 2; ++dt)
          at[pt][dt] = (f32x4){0.f, 0.f, 0.f, 0.f};
      #pragma unroll
      for (int qt = 0; qt < 4; ++qt) {
        f16x4 vf0 = *(const f16x4*)(lds + LDS_VT + swz128(h * 32 + li, qt * 32 + g * 8));
        f16x4 vf1 = *(const f16x4*)(lds + LDS_VT + swz128(h * 32 + 16 + li, qt * 32 + g * 8));
        #pragma unroll
        for (int pt = 0; pt < 2; ++pt) {
          at[pt][0] = mfmah16(vf0, pa[pt][qt], at[pt][0]);
          at[pt][1] = mfmah16(vf1, pa[pt][qt], at[pt][1]);
        }
      }

      // attn fp16 store into Q region (disjoint rows/cols across waves; see analysis)
      #pragma unroll
      for (int pt = 0; pt < 2; ++pt)
        #pragma unroll
        for (int dt = 0; dt < 2; ++dt) {
          const f32x4 a4 = at[pt][dt];
          u32x2 hh;
          hh.x = cvt2h(a4[0] * rinv[pt], a4[1] * rinv[pt]);
          hh.y = cvt2h(a4[2] * rinv[pt], a4[3] * rinv[pt]);
          *(u32x2*)(lds + LDS_Q + swz256(p0 + pt * 16 + li, h * 64 + dt * 32 + g * 8)) = hh;
        }
    }
    __syncthreads();

    // ---- Phase 3 (half hf): partial out-proj (k = hf*128..hf*128+127), fp16.
    //      Wave w owns 2 col-blocks; accumulate into persistent acc2. ----
    {
      #pragma unroll
      for (int kk = 0; kk < 4; ++kk) {
        s16x8 a[4];
        #pragma unroll
        for (int rb = 0; rb < 4; ++rb)
          a[rb] = *(const s16x8*)(lds + LDS_Q + swz256(rb * 16 + li, kk * 64 + g * 16));
        #pragma unroll
        for (int c = 0; c < 2; ++c) {
          s16x8 bc = *(const s16x8*)(wH + (size_t)((w * 2 + c) * 16 + li) * 256
                                     + hf * 128 + kk * 32 + g * 8);
          #pragma unroll
          for (int rb = 0; rb < 4; ++rb)
            acc2[c][rb] = mfma16h(a[rb], bc, acc2[c][rb]);
        }
      }
    }
    if (hf == 0) __syncthreads();   // protect Q/K/VT regions before next half's phase 1
  }

  // ---- Epilogue: direct rolled stores (r12-proven clean: WRITE == out size) ----
  #pragma unroll
  for (int c = 0; c < 2; ++c) {
    const int n = (w * 2 + c) * 16 + li;
    const float bo = bout[n];
    #pragma unroll
    for (int rb = 0; rb < 4; ++rb)
      #pragma unroll
      for (int r = 0; r < 4; ++r) {
        int m = rb * 16 + g * 4 + r;
        int pi = m >> 3, pj = m & 7;
        int dr = (wh * 8 + pi + 4) & 255;
        int dc = (wwi * 8 + pj + 4) & 255;
        out[(((size_t)b * 256 + dr) * 256 + dc) * 256 + n] = acc2[c][rb][r] + bo;
      }
  }
}

extern "C" void kernel_launch(void* const* d_in, const int* in_sizes, int n_in,
                              void* d_out, int out_size, void* d_ws, size_t ws_size,
                              hipStream_t stream) {
  (void)in_sizes; (void)n_in; (void)out_size; (void)ws_size;
  const float* x    = (const float*)d_in[0];
  const float* Wqkv = (const float*)d_in[1];
  const float* bqkv = (const float*)d_in[2];
  const float* relp = (const float*)d_in[3];
  const float* Wout = (const float*)d_in[4];
  const float* bout = (const float*)d_in[5];
  float* out = (float*)d_out;

  short* wqkvT = (short*)d_ws;                  // 768*256 bf16
  short* wH    = wqkvT + 768 * 256;             // 256*256 fp16
  float* relt  = (float*)(wH + 256 * 256);      // 4*8*4*4*256 f32 = 512KB

  hipLaunchKernelGGL(prep_w, dim3(1536), dim3(256), 0, stream,
                     Wqkv, Wout, relp, wqkvT, wH, relt);
  hipLaunchKernelGGL(swin_mfma, dim3(4096), dim3(512), 0, stream,
                     x, bqkv, bout, wqkvT, wH, relt, out);
}

// Round 14
// 390.217 us; speedup vs baseline: 1.6709x; 1.6709x over previous
//
#include <hip/hip_runtime.h>
#include <hip/hip_bf16.h>

typedef __attribute__((ext_vector_type(4))) float f32x4;
typedef __attribute__((ext_vector_type(2))) unsigned int u32x2;
typedef __attribute__((ext_vector_type(8))) short s16x8;
typedef __attribute__((ext_vector_type(8))) __bf16 bf16v8;
typedef __attribute__((ext_vector_type(8))) _Float16 f16v8;
typedef __attribute__((ext_vector_type(4))) _Float16 f16x4;

// LDS layout (bytes)
#define LDS_XS 0        // 32768: x window bf16 [64][256] swz512; phase2+: attn fp16
#define LDS_QS 32768    // 32768: Q bf16 [64][256] (pre-scaled) swz512
#define LDS_KS 65536    // 32768: K bf16 [64][256], swz512
#define LDS_VT 98304    // 32768: V^T fp16 [256][64], swz128
#define LDS_TOT 131072

__device__ __forceinline__ f32x4 mfma16(s16x8 a, s16x8 b, f32x4 c) {
  return __builtin_amdgcn_mfma_f32_16x16x32_bf16(
      __builtin_bit_cast(bf16v8, a), __builtin_bit_cast(bf16v8, b), c, 0, 0, 0);
}
__device__ __forceinline__ f32x4 mfma16h(s16x8 a, s16x8 b, f32x4 c) {
  return __builtin_amdgcn_mfma_f32_16x16x32_f16(
      __builtin_bit_cast(f16v8, a), __builtin_bit_cast(f16v8, b), c, 0, 0, 0);
}
__device__ __forceinline__ f32x4 mfmah16(f16x4 a, f16x4 b, f32x4 c) {
  return __builtin_amdgcn_mfma_f32_16x16x16f16(a, b, c, 0, 0, 0);
}

// HW pair converts
__device__ __forceinline__ unsigned int cvt2(float a, float b) {   // 2x bf16, RNE
  __hip_bfloat162 r = __float22bfloat162_rn(make_float2(a, b));
  unsigned int u;
  __builtin_memcpy(&u, &r, 4);
  return u;
}
__device__ __forceinline__ unsigned int cvt2h(float a, float b) {  // 2x fp16, RTZ
  auto r = __builtin_amdgcn_cvt_pkrtz(a, b);
  unsigned int u;
  __builtin_memcpy(&u, &r, 4);
  return u;
}
__device__ __forceinline__ f16x4 pack4h(float a, float b, float c, float d) {
  u32x2 u;
  u.x = cvt2h(a, b);
  u.y = cvt2h(c, d);
  f16x4 r;
  __builtin_memcpy(&r, &u, 8);
  return r;
}

__device__ __forceinline__ short f2bf(float f) {
  unsigned u = __float_as_uint(f);
  u += 0x7fffu + ((u >> 16) & 1u);
  return (short)(u >> 16);
}

__device__ __forceinline__ int swz512(int row, int colByte) {
  return row * 512 + (colByte ^ ((row & 7) << 4));
}
__device__ __forceinline__ int swz128(int row, int colByte) {
  return row * 128 + (colByte ^ ((row & 7) << 4));
}

// Prep: WqkvT[n][k] bf16 (768x256); WoutT[n][k] fp16 (256x256);
// RELT[var][h][qt][strip][lane][r] f32 = masked rel_pos in simT C-frag order.
__global__ void prep_w(const float* __restrict__ Wqkv, const float* __restrict__ Wout,
                       const float* __restrict__ relp,
                       short* __restrict__ wqkvT, short* __restrict__ wH,
                       float* __restrict__ relt) {
  int t = blockIdx.x * 256 + threadIdx.x;
  if (t < 768 * 256) {
    int n = t >> 8, k = t & 255;
    wqkvT[t] = f2bf(Wqkv[k * 768 + n]);
  } else if (t < 768 * 256 + 256 * 256) {
    int t2 = t - 768 * 256;
    int n = t2 >> 8, k = t2 & 255;
    _Float16 h = (_Float16)Wout[k * 256 + n];
    unsigned short us;
    __builtin_memcpy(&us, &h, 2);
    wH[t2] = (short)us;
  } else {
    int u = t - 768 * 256 - 256 * 256;   // 0 .. 131071
    int r = u & 3, l = (u >> 2) & 63, strip = (u >> 8) & 3;
    int qt = (u >> 10) & 3, h = (u >> 12) & 7, var = (u >> 15) & 3;
    int p = strip * 16 + (l & 15);
    int q = qt * 16 + ((l >> 4) << 2) + r;
    int pi = p >> 3, pj = p & 7, qi = q >> 3, qj = q & 7;
    bool mrow = (var >> 1) & 1, mcol = var & 1;
    bool mk = (mrow && ((pi < 4) != (qi < 4))) || (mcol && ((pj < 4) != (qj < 4)));
    relt[u] = mk ? -1e30f : relp[h * 225 + (pi - qi + 7) * 15 + (pj - qj + 7)];
  }
}

// One block per (batch, window). 512 threads = 8 waves (2/SIMD -> 256-reg budget;
// 4 waves/SIMD hard-caps at 128 unified regs and spills ~1GB to scratch, r13).
__global__ __launch_bounds__(512, 2) void swin_mfma(
    const float* __restrict__ x, const float* __restrict__ bqkv,
    const float* __restrict__ bout,
    const short* __restrict__ wqkvT, const short* __restrict__ wH,
    const float* __restrict__ relt, float* __restrict__ out)
{
  __shared__ __align__(16) char lds[LDS_TOT];

  const int tx = threadIdx.x;
  const int w  = tx >> 6;         // wave 0..7
  const int l  = tx & 63;         // lane
  const int g  = l >> 4;          // k-group 0..3
  const int li = l & 15;          // row/col within fragment

  const int b   = blockIdx.x >> 10;
  const int wdw = blockIdx.x & 1023;
  const int wh  = wdw >> 5, wwi = wdw & 31;

  // ---- Phase 0: stage x window (rolled -4) as bf16 into LDS ----
  for (int i = 0; i < 8; ++i) {
    int idx = tx + i * 512;       // 0..4095
    int p = idx >> 6, c4 = idx & 63;
    int pi = p >> 3, pj = p & 7;
    int sr = (wh * 8 + pi + 4) & 255;
    int sc = (wwi * 8 + pj + 4) & 255;
    f32x4 v = *(const f32x4*)(x + ((((size_t)b * 256 + sr) * 256 + sc) * 256 + c4 * 4));
    u32x2 uu;
    uu.x = cvt2(v[0], v[1]);
    uu.y = cvt2(v[2], v[3]);
    *(u32x2*)(lds + LDS_XS + swz512(p, c4 * 8)) = uu;
  }

  // hoisted: phase-1 initial B fragments (global, no LDS dependency)
  int ocol[6];
  #pragma unroll
  for (int j = 0; j < 4; ++j) ocol[j] = (w * 4 + j) * 16 + li;
  #pragma unroll
  for (int j = 4; j < 6; ++j) ocol[j] = 512 + (w * 2 + (j - 4)) * 16 + li;
  s16x8 bcur[6];
  #pragma unroll
  for (int j = 0; j < 6; ++j)
    bcur[j] = *(const s16x8*)(wqkvT + (size_t)ocol[j] * 256 + g * 8);

  __syncthreads();

  // ---- Phase 1: QKV GEMM. Wave w: Q/K col-blocks w*4..w*4+3 (swapped operands),
  //      V col-blocks w*2, w*2+1 (normal). A double-buffered, B 1-deep prefetch. ----
  {
    f32x4 acc[6][4];
    #pragma unroll
    for (int j = 0; j < 6; ++j)
      #pragma unroll
      for (int rb = 0; rb < 4; ++rb)
        acc[j][rb] = (f32x4){0.f, 0.f, 0.f, 0.f};

    s16x8 a[2][4];
    #pragma unroll
    for (int rb = 0; rb < 4; ++rb)
      a[0][rb] = *(const s16x8*)(lds + LDS_XS + swz512(rb * 16 + li, g * 16));

    #pragma unroll
    for (int kk = 0; kk < 8; ++kk) {
      const int cur = kk & 1;
      s16x8 bnext[6];
      if (kk < 7) {
        #pragma unroll
        for (int rb = 0; rb < 4; ++rb)
          a[cur ^ 1][rb] = *(const s16x8*)(lds + LDS_XS
                                           + swz512(rb * 16 + li, (kk + 1) * 64 + g * 16));
        #pragma unroll
        for (int j = 0; j < 6; ++j)
          bnext[j] = *(const s16x8*)(wqkvT + (size_t)ocol[j] * 256 + (kk + 1) * 32 + g * 8);
      }
      #pragma unroll
      for (int j = 0; j < 4; ++j)          // Q,K: swapped -> C[outcol][token]
        #pragma unroll
        for (int rb = 0; rb < 4; ++rb)
          acc[j][rb] = mfma16(bcur[j], a[cur][rb], acc[j][rb]);
      #pragma unroll
      for (int j = 4; j < 6; ++j)          // V: normal -> C[token][vcol]
        #pragma unroll
        for (int rb = 0; rb < 4; ++rb)
          acc[j][rb] = mfma16(a[cur][rb], bcur[j], acc[j][rb]);
      if (kk < 7) {
        #pragma unroll
        for (int j = 0; j < 6; ++j) bcur[j] = bnext[j];
      }
    }

    // Packed b64 stores.
    #pragma unroll
    for (int j = 0; j < 4; ++j) {          // Q or K: row=token(rb*16+li), 4 consec cols
      const int cb = w * 4 + j;
      if (cb < 16) {                       // Q (pre-scaled)
        f32x4 bq = *(const f32x4*)(bqkv + cb * 16 + g * 4);
        #pragma unroll
        for (int rb = 0; rb < 4; ++rb) {
          const float SC = 0.17677669529663687f;
          u32x2 uu;
          uu.x = cvt2((acc[j][rb][0] + bq[0]) * SC, (acc[j][rb][1] + bq[1]) * SC);
          uu.y = cvt2((acc[j][rb][2] + bq[2]) * SC, (acc[j][rb][3] + bq[3]) * SC);
          *(u32x2*)(lds + LDS_QS + swz512(rb * 16 + li, cb * 32 + g * 8)) = uu;
        }
      } else {                             // K
        f32x4 bk = *(const f32x4*)(bqkv + cb * 16 + g * 4);
        #pragma unroll
        for (int rb = 0; rb < 4; ++rb) {
          u32x2 uu;
          uu.x = cvt2(acc[j][rb][0] + bk[0], acc[j][rb][1] + bk[1]);
          uu.y = cvt2(acc[j][rb][2] + bk[2], acc[j][rb][3] + bk[3]);
          *(u32x2*)(lds + LDS_KS + swz512(rb * 16 + li, (cb - 16) * 32 + g * 8)) = uu;
        }
      }
    }
    #pragma unroll
    for (int j = 4; j < 6; ++j) {          // V -> VT[d][token] fp16
      const int d = (w * 2 + (j - 4)) * 16 + li;
      const float bv = bqkv[512 + d];
      #pragma unroll
      for (int rb = 0; rb < 4; ++rb) {
        u32x2 uu;
        uu.x = cvt2h(acc[j][rb][0] + bv, acc[j][rb][1] + bv);
        uu.y = cvt2h(acc[j][rb][2] + bv, acc[j][rb][3] + bv);
        *(u32x2*)(lds + LDS_VT + swz128(d, rb * 32 + g * 8)) = uu;
      }
    }
  }
  __syncthreads();

  // ---- Phase 2: attention, 2 units per wave. Inputs for BOTH units preloaded
  //      (independent chains overlap); compute serial. In-register P'->PV. ----
  {
    const int rvar = ((wh == 31) ? 2 : 0) | ((wwi == 31) ? 1 : 0);
    const int phalf = w & 1, p0 = phalf * 32;

    f32x4 rc2[2][2][4];
    s16x8 qf2[2][2], kf2[2][4];
    f16x4 vf2[2][2][4];
    #pragma unroll
    for (int u = 0; u < 2; ++u) {
      const int h = (w >> 1) + u * 4;
      #pragma unroll
      for (int pt = 0; pt < 2; ++pt)
        qf2[u][pt] = *(const s16x8*)(lds + LDS_QS + swz512(p0 + pt * 16 + li, h * 64 + g * 16));
      #pragma unroll
      for (int qt = 0; qt < 4; ++qt)
        kf2[u][qt] = *(const s16x8*)(lds + LDS_KS + swz512(qt * 16 + li, h * 64 + g * 16));
      #pragma unroll
      for (int dt = 0; dt < 2; ++dt)
        #pragma unroll
        for (int qt = 0; qt < 4; ++qt)
          vf2[u][dt][qt] = *(const f16x4*)(lds + LDS_VT
                                           + swz128(h * 32 + dt * 16 + li, qt * 32 + g * 8));
      #pragma unroll
      for (int pt = 0; pt < 2; ++pt)
        #pragma unroll
        for (int qt = 0; qt < 4; ++qt)
          rc2[u][pt][qt] = *(const f32x4*)(relt
              + ((((rvar * 8 + h) * 4 + qt) * 4 + (phalf * 2 + pt)) * 64 + l) * 4);
    }

    #pragma unroll
    for (int u = 0; u < 2; ++u) {
      const int h = (w >> 1) + u * 4;

      f32x4 simT[2][4];
      #pragma unroll
      for (int pt = 0; pt < 2; ++pt)
        #pragma unroll
        for (int qt = 0; qt < 4; ++qt)
          simT[pt][qt] = mfma16(kf2[u][qt], qf2[u][pt], rc2[u][pt][qt]);

      float rinv[2];
      f16x4 pa[2][4];
      #pragma unroll
      for (int pt = 0; pt < 2; ++pt) {
        float s = 0.f;
        #pragma unroll
        for (int qt = 0; qt < 4; ++qt) {
          float e0 = __expf(simT[pt][qt][0]);
          float e1 = __expf(simT[pt][qt][1]);
          float e2 = __expf(simT[pt][qt][2]);
          float e3 = __expf(simT[pt][qt][3]);
          s += (e0 + e1) + (e2 + e3);
          pa[pt][qt] = pack4h(e0, e1, e2, e3);
        }
        s += __shfl_xor(s, 16);
        s += __shfl_xor(s, 32);
        rinv[pt] = 1.0f / s;
      }

      f32x4 at[2][2];
      #pragma unroll
      for (int pt = 0; pt < 2; ++pt)
        #pragma unroll
        for (int dt = 0; dt < 2; ++dt)
          at[pt][dt] = (f32x4){0.f, 0.f, 0.f, 0.f};
      #pragma unroll
      for (int qt = 0; qt < 4; ++qt)
        #pragma unroll
        for (int pt = 0; pt < 2; ++pt)
          #pragma unroll
          for (int dt = 0; dt < 2; ++dt)
            at[pt][dt] = mfmah16(vf2[u][dt][qt], pa[pt][qt], at[pt][dt]);

      // attn fp16 packed store into XS (x dead): row = p, 4 consecutive d per (g,r)
      #pragma unroll
      for (int pt = 0; pt < 2; ++pt)
        #pragma unroll
        for (int dt = 0; dt < 2; ++dt) {
          const f32x4 a4 = at[pt][dt];
          u32x2 hh;
          hh.x = cvt2h(a4[0] * rinv[pt], a4[1] * rinv[pt]);
          hh.y = cvt2h(a4[2] * rinv[pt], a4[3] * rinv[pt]);
          *(u32x2*)(lds + LDS_XS + swz512(p0 + pt * 16 + li, h * 64 + dt * 32 + g * 8)) = hh;
        }
    }
  }
  __syncthreads();

  // ---- Phase 3: out-proj, single-term fp16. Wave w owns 2 col-blocks.
  //      A double-buffered, B 1-deep prefetch. Direct rolled stores (clean). ----
  {
    f32x4 acc2[2][4];
    #pragma unroll
    for (int c = 0; c < 2; ++c)
      #pragma unroll
      for (int rb = 0; rb < 4; ++rb)
        acc2[c][rb] = (f32x4){0.f, 0.f, 0.f, 0.f};

    s16x8 bc[2];
    #pragma unroll
    for (int c = 0; c < 2; ++c)
      bc[c] = *(const s16x8*)(wH + (size_t)((w * 2 + c) * 16 + li) * 256 + g * 8);

    s16x8 a[2][4];
    #pragma unroll
    for (int rb = 0; rb < 4; ++rb)
      a[0][rb] = *(const s16x8*)(lds + LDS_XS + swz512(rb * 16 + li, g * 16));

    #pragma unroll
    for (int kk = 0; kk < 8; ++kk) {
      const int cur = kk & 1;
      s16x8 bn[2];
      if (kk < 7) {
        #pragma unroll
        for (int rb = 0; rb < 4; ++rb)
          a[cur ^ 1][rb] = *(const s16x8*)(lds + LDS_XS
                                           + swz512(rb * 16 + li, (kk + 1) * 64 + g * 16));
        #pragma unroll
        for (int c = 0; c < 2; ++c)
          bn[c] = *(const s16x8*)(wH + (size_t)((w * 2 + c) * 16 + li) * 256
                                  + (kk + 1) * 32 + g * 8);
      }
      #pragma unroll
      for (int c = 0; c < 2; ++c)
        #pragma unroll
        for (int rb = 0; rb < 4; ++rb)
          acc2[c][rb] = mfma16h(a[cur][rb], bc[c], acc2[c][rb]);
      if (kk < 7) {
        #pragma unroll
        for (int c = 0; c < 2; ++c) bc[c] = bn[c];
      }
    }

    #pragma unroll
    for (int c = 0; c < 2; ++c) {
      const int n = (w * 2 + c) * 16 + li;
      const float bo = bout[n];
      #pragma unroll
      for (int rb = 0; rb < 4; ++rb)
        #pragma unroll
        for (int r = 0; r < 4; ++r) {
          int m = rb * 16 + g * 4 + r;
          int pi = m >> 3, pj = m & 7;
          int dr = (wh * 8 + pi + 4) & 255;
          int dc = (wwi * 8 + pj + 4) & 255;
          out[(((size_t)b * 256 + dr) * 256 + dc) * 256 + n] = acc2[c][rb][r] + bo;
        }
    }
  }
}

extern "C" void kernel_launch(void* const* d_in, const int* in_sizes, int n_in,
                              void* d_out, int out_size, void* d_ws, size_t ws_size,
                              hipStream_t stream) {
  (void)in_sizes; (void)n_in; (void)out_size; (void)ws_size;
  const float* x    = (const float*)d_in[0];
  const float* Wqkv = (const float*)d_in[1];
  const float* bqkv = (const float*)d_in[2];
  const float* relp = (const float*)d_in[3];
  const float* Wout = (const float*)d_in[4];
  const float* bout = (const float*)d_in[5];
  float* out = (float*)d_out;

  short* wqkvT = (short*)d_ws;                  // 768*256 bf16
  short* wH    = wqkvT + 768 * 256;             // 256*256 fp16
  float* relt  = (float*)(wH + 256 * 256);      // 4*8*4*4*256 f32 = 512KB

  hipLaunchKernelGGL(prep_w, dim3(1536), dim3(256), 0, stream,
                     Wqkv, Wout, relp, wqkvT, wH, relt);
  hipLaunchKernelGGL(swin_mfma, dim3(4096), dim3(512), 0, stream,
                     x, bqkv, bout, wqkvT, wH, relt, out);
}